// Round 17
// baseline (189.543 us; speedup 1.0000x reference)
//
#include <hip/hip_runtime.h>

#define NN 40000
#define NE 640000
#define F 128
#define NC 16
#define NT 32    // nodes per tile
#define TPB 5    // tiles per persistent block (250 blocks x 5 x 32 = 40000)

typedef __attribute__((ext_vector_type(8))) short bf16x8;
typedef __attribute__((ext_vector_type(4))) float f32x4;

// ws layout (bytes); total 23501312 < proven 23632384
#define OFF_ROWPTR 0u
#define OFF_FILL   163968u     // NN ints; DEAD after k_scatter -> first 256 f32 reused as biasA/biasE
#define OFF_BSUM   327936u
#define OFF_SORTED 328192u
#define OFF_STATS  2888192u    // 512 f32: [sum][sumsq][..][..] (sums stay intact)
#define OFF_W1B    2890240u    // w1l | w1r bf16 [out][k] (64 KB)
#define OFF_W2B    2955776u    // w2l | w2r bf16 [out][k], BN-scaled (64 KB)
#define OFF_XB     3021312u    // NN*F bf16: xb, then h1 overwrites same rows
#define OFF_AGGM   13261312u   // NN*F bf16

// LDS regions (k_gemm)
#define SM_W   0u        // weights 64 KB (swizzled image)
#define SM_A0  65536u    // A dbuf 0: agg 8K | self 8K
#define SM_A1  81920u    // A dbuf 1
#define SM_C   98304u    // sC [32][132] f32 = 16896 B
#define SM_TOT 115200u

#define GLL(gsrc, ldst) \
    __builtin_amdgcn_global_load_lds((const __attribute__((address_space(1))) void*)(gsrc), \
        (__attribute__((address_space(3))) void*)(ldst), 16, 0, 0)

__device__ __forceinline__ unsigned short f2b(float f) {   // f32 -> bf16 RNE
    unsigned u = __builtin_bit_cast(unsigned, f);
    return (unsigned short)((u + 0x7fffu + ((u >> 16) & 1u)) >> 16);
}
__device__ __forceinline__ float b2f(unsigned short s) {
    return __builtin_bit_cast(float, (unsigned)s << 16);
}
__device__ __forceinline__ unsigned pk2(float lo, float hi) {
    return (unsigned)f2b(lo) | ((unsigned)f2b(hi) << 16);
}
__device__ __forceinline__ float blo(unsigned u) { return __builtin_bit_cast(float, u << 16); }
__device__ __forceinline__ float bhi(unsigned u) { return __builtin_bit_cast(float, u & 0xffff0000u); }

// Fused prep: x->bf16 (8 elems/thread), W1 -> bf16, zero fill+stats.
__global__ __launch_bounds__(256) void k_prep(const float* __restrict__ x, unsigned short* __restrict__ xb,
                                              const float* __restrict__ W1l, const float* __restrict__ W1r,
                                              unsigned short* __restrict__ w1b,
                                              int* __restrict__ fill, float* __restrict__ stats) {
    int gid = blockIdx.x * 256 + threadIdx.x;    // < 640000
    if (gid < NN) fill[gid] = 0;
    if (gid < 256) stats[gid] = 0.f;
    if (gid < 32768) {
        int m = gid >> 14, rc = gid & 16383;
        const float* src = m ? W1r : W1l;
        w1b[gid] = f2b(src[rc]);
    }
    int i = gid * 8;
    float4 lo = *(const float4*)&x[i];
    float4 hi = *(const float4*)&x[i + 4];
    uint4 o;
    o.x = pk2(lo.x, lo.y); o.y = pk2(lo.z, lo.w);
    o.z = pk2(hi.x, hi.y); o.w = pk2(hi.z, hi.w);
    *(uint4*)&xb[i] = o;
}

__global__ __launch_bounds__(256) void k_hist(const int* __restrict__ ei, int* __restrict__ cnt) {
    int e = blockIdx.x * 256 + threadIdx.x;
    if (e < NE) atomicAdd(&cnt[ei[NE + e]], 1);
}

__global__ __launch_bounds__(1024) void k_scan1(const int* __restrict__ cnt, int* __restrict__ rowptr,
                                                int* __restrict__ bsum) {
    __shared__ int wsum[16];
    int t = threadIdx.x, b = blockIdx.x;
    int idx = b * 1024 + t;
    int v = (idx < NN) ? cnt[idx] : 0;
    int lane = t & 63, w = t >> 6;
    int val = v;
    #pragma unroll
    for (int off = 1; off < 64; off <<= 1) { int u = __shfl_up(val, off); if (lane >= off) val += u; }
    if (lane == 63) wsum[w] = val;
    __syncthreads();
    if (w == 0) {
        int x = (lane < 16) ? wsum[lane] : 0;
        #pragma unroll
        for (int off = 1; off < 16; off <<= 1) { int u = __shfl_up(x, off); if (lane >= off) x += u; }
        if (lane < 16) wsum[lane] = x;
    }
    __syncthreads();
    int excl = val - v + (w > 0 ? wsum[w - 1] : 0);
    if (idx < NN) rowptr[idx] = excl;
    if (t == 1023) bsum[b] = wsum[15];
}

// scan2 folded in: every wave redundantly exclusive-scans the 40 block sums.
__global__ __launch_bounds__(1024) void k_scan3(int* __restrict__ rowptr, const int* __restrict__ bsum,
                                                int* __restrict__ fill) {
    int t = threadIdx.x, b = blockIdx.x;
    int lane = t & 63;
    int v = (lane < 40) ? bsum[lane] : 0;
    int val = v;
    #pragma unroll
    for (int off = 1; off < 64; off <<= 1) { int u = __shfl_up(val, off); if (lane >= off) val += u; }
    int base = __shfl(val - v, b);
    int idx = b * 1024 + t;
    if (idx < NN) {
        int r = rowptr[idx] + base;
        rowptr[idx] = r;
        fill[idx] = r;
    }
    if (b == 0 && t == 0) rowptr[NN] = NE;
}

__global__ __launch_bounds__(256) void k_scatter(const int* __restrict__ ei, int* __restrict__ fill,
                                                 int* __restrict__ sorted) {
    int e = blockIdx.x * 256 + threadIdx.x;
    if (e < NE) {
        int src = ei[e], dst = ei[NE + e];
        int pos = atomicAdd(&fill[dst], 1);
        sorted[pos] = src;
    }
}

// Parallel BN-fold: 256 blocks x 128 threads; block = (side, output col o).
__global__ __launch_bounds__(128) void k_wprep2(const float* __restrict__ W2l, const float* __restrict__ W2r,
                                                const float* __restrict__ b2l,
                                                const float* __restrict__ gamma, const float* __restrict__ beta,
                                                const float* __restrict__ stats,
                                                unsigned short* __restrict__ w2b,
                                                float* __restrict__ biasAE) {
    __shared__ float red[2];
    int b = blockIdx.x;
    int side = b >> 7, o = b & 127;   // side 0 = W2l (-> biasE), side 1 = W2r (-> biasA)
    int k = threadIdx.x;
    float mu  = stats[k] * (1.f / NN);
    float var = stats[F + k] * (1.f / NN) - mu * mu;
    float a = gamma[k] * rsqrtf(var + 1e-5f);
    float bb = beta[k] - mu * a;
    const float* W = side ? W2r : W2l;
    float w = W[o * F + k];
    w2b[(side ? 16384 : 0) + o * F + k] = f2b(w * a);
    float d = bb * w;
    #pragma unroll
    for (int off = 1; off < 64; off <<= 1) d += __shfl_xor(d, off);
    if ((k & 63) == 0) red[k >> 6] = d;
    __syncthreads();
    if (k == 0) {
        float dot = red[0] + red[1];
        if (side) biasAE[o] = b2l[o] + dot;        // bias2a (always applied)
        else      biasAE[128 + o] = dot;           // biasExtra (iff deg>0)
    }
}

// Gather (neighbor mean): one wave per node; quarter q, up to 4 rows in flight per lane.
// (r15-proven version; r16's shuffle-window restructure regressed ~5us — agg is BW-bound,
// not index-latency-bound, so the extra shfl/predicate ops were pure overhead.)
__global__ __launch_bounds__(256) void k_agg(
    const unsigned short* __restrict__ featb,
    const int* __restrict__ rowptr, const int* __restrict__ sorted,
    unsigned short* __restrict__ aggm)
{
    int node = (blockIdx.x << 2) + (threadIdx.x >> 6);
    int lane = threadIdx.x & 63;
    int q = lane >> 4, li = lane & 15;
    int fo = li << 3;
    int e0 = rowptr[node], e1 = rowptr[node + 1];
    int deg = e1 - e0;
    float a0=0.f,a1=0.f,a2=0.f,a3=0.f,a4=0.f,a5=0.f,a6=0.f,a7=0.f;

#define ACC_EDGE(SRC) do { \
        uint4 u = *(const uint4*)&featb[(size_t)(SRC) * F + fo]; \
        a0 += blo(u.x); a1 += bhi(u.x); \
        a2 += blo(u.y); a3 += bhi(u.y); \
        a4 += blo(u.z); a5 += bhi(u.z); \
        a6 += blo(u.w); a7 += bhi(u.w); \
    } while (0)

    int e = e0;
    for (; e + 16 <= e1; e += 16) {
        int s0 = sorted[e + q];
        int s1 = sorted[e + 4 + q];
        int s2 = sorted[e + 8 + q];
        int s3 = sorted[e + 12 + q];
        ACC_EDGE(s0); ACC_EDGE(s1); ACC_EDGE(s2); ACC_EDGE(s3);
    }
    for (; e + 8 <= e1; e += 8) {
        int s0 = sorted[e + q];
        int s1 = sorted[e + 4 + q];
        ACC_EDGE(s0); ACC_EDGE(s1);
    }
    for (; e + 4 <= e1; e += 4) {
        int s0 = sorted[e + q];
        ACC_EDGE(s0);
    }
    if (e < e1 && q < (e1 - e)) {
        int s0 = sorted[e + q];
        ACC_EDGE(s0);
    }
#undef ACC_EDGE

    #pragma unroll
    for (int m = 16; m <= 32; m <<= 1) {
        a0 += __shfl_xor(a0, m); a1 += __shfl_xor(a1, m);
        a2 += __shfl_xor(a2, m); a3 += __shfl_xor(a3, m);
        a4 += __shfl_xor(a4, m); a5 += __shfl_xor(a5, m);
        a6 += __shfl_xor(a6, m); a7 += __shfl_xor(a7, m);
    }

    if (q == 0) {
        float inv = 1.f / (float)(deg > 1 ? deg : 1);
        uint4 o;
        o.x = pk2(a0 * inv, a1 * inv);
        o.y = pk2(a2 * inv, a3 * inv);
        o.z = pk2(a4 * inv, a5 * inv);
        o.w = pk2(a6 * inv, a7 * inv);
        *(uint4*)&aggm[(size_t)node * F + fo] = o;
    }
}

// Persistent MFMA dual GEMM — 512 threads / 8 waves per block (r15-proven).
// Wave w -> 16 cols [w*16, w*16+16), rows 0..31. Weights staged ONCE per block
// (async global_load_lds, linear dest + pre-swizzled src); 5 tiles with A dbuf.
// Conv1 BN-stats pass now uses all 512 threads (4 row-groups x 128 cols).
template<int CONV2>
__global__ __launch_bounds__(512) void k_gemm(
    const unsigned short* __restrict__ aggm,
    const unsigned short* __restrict__ selfb,   // conv1: xb, conv2: h1
    const unsigned short* __restrict__ wb,      // wl | wr bf16 [out][k], 64KB
    const float* __restrict__ bias1,
    const float* __restrict__ biasA, const float* __restrict__ biasE,
    const int* __restrict__ rowptr,
    unsigned short* __restrict__ h1, float* __restrict__ stats,
    const float* __restrict__ Wfc, const float* __restrict__ bfc,
    float* __restrict__ out)
{
    __shared__ __align__(16) char smem[SM_TOT];
    int t = threadIdx.x;
    int nb0 = blockIdx.x * (NT * TPB);
    int w = t >> 6, lane = t & 63;
    int li = lane & 15, kg = lane >> 4;
    float (*sC)[132] = (float(*)[132])(smem + SM_C);

    // ---- weight stage (once): 8 async 1KB calls per wave ----
    {
        const char* wsrc = (const char*)wb;
        #pragma unroll
        for (int i = 0; i < 8; ++i) {
            unsigned Lb = (unsigned)(w * 8192 + i * 1024);
            unsigned s = Lb + (unsigned)lane * 16u;
            unsigned g = s ^ (((s >> 8) & 7u) << 4);
            GLL(wsrc + g, smem + Lb);
        }
    }

    // A tile stage: 16 KB over 8 waves (2 x 1KB each); waves 0-3 agg, waves 4-7 self
#define STAGE_A(TI, BUF) { \
        size_t rowb = (size_t)(nb0 + (TI) * NT) * 256u; \
        const char* src_ = (const char*)((w < 4) ? aggm : selfb) + rowb; \
        unsigned sub_ = (unsigned)((w & 3) * 2048); \
        _Pragma("unroll") \
        for (int i_ = 0; i_ < 2; ++i_) { \
            unsigned q_ = sub_ + (unsigned)(i_ * 1024); \
            unsigned s_ = q_ + (unsigned)lane * 16u; \
            unsigned g_ = s_ ^ (((s_ >> 8) & 7u) << 4); \
            GLL(src_ + g_, smem + (BUF) + ((w < 4) ? 0u : 8192u) + q_); \
        } }

    STAGE_A(0, SM_A0)
    __syncthreads();   // vmcnt drained before barrier: weights + tile0 in LDS

    float sAcc = 0.f, s2Acc = 0.f;   // conv1 BN stats, accumulated across tiles
    unsigned swz = ((unsigned)(li & 7) << 4);
    int scol = t & 127, srow0 = (t >> 7) * 8;   // conv1 stats decomposition (512 threads)

    for (int tt = 0; tt < TPB; ++tt) {
        unsigned bufC = (tt & 1) ? SM_A1 : SM_A0;
        unsigned bufN = (tt & 1) ? SM_A0 : SM_A1;
        if (tt + 1 < TPB) STAGE_A(tt + 1, bufN)   // async, lands by next barrier

        int nb = nb0 + tt * NT;

        // ---- MFMA: wave w -> cols [w*16, w*16+16), rows 0..31 ----
        f32x4 acc0 = {0.f,0.f,0.f,0.f}, acc1 = {0.f,0.f,0.f,0.f};
        #pragma unroll
        for (int path = 0; path < 2; ++path) {
            unsigned aBase = bufC + (path ? 8192u : 0u);
            unsigned bBase = path ? 32768u : 0u;
            #pragma unroll
            for (int kc = 0; kc < 4; ++kc) {
                unsigned koff = (unsigned)(kg * 16 + kc * 64);
                bf16x8 a0 = *(const bf16x8*)(smem + aBase + (((unsigned)li * 256u + koff) ^ swz));
                bf16x8 a1 = *(const bf16x8*)(smem + aBase + (((unsigned)(16 + li) * 256u + koff) ^ swz));
                bf16x8 b0 = *(const bf16x8*)(smem + bBase + (((unsigned)(w * 16 + li) * 256u + koff) ^ swz));
                acc0 = __builtin_amdgcn_mfma_f32_16x16x32_bf16(a0, b0, acc0, 0, 0, 0);
                acc1 = __builtin_amdgcn_mfma_f32_16x16x32_bf16(a1, b0, acc1, 0, 0, 0);
            }
        }
        __syncthreads();   // B1: compute-cur done; next-tile async loads drained

        // ---- C -> sC (layout r6/r11-verified: reg r -> row kg*4+r, col li) ----
        #pragma unroll
        for (int r = 0; r < 4; ++r) {
            sC[kg * 4 + r][w * 16 + li]      = acc0[r];
            sC[16 + kg * 4 + r][w * 16 + li] = acc1[r];
        }
        __syncthreads();   // B2

        // ---- bias + row L2 norm: thread -> row t>>4, cols (t&15)*8..+8 ----
        int row = t >> 4, cb = (t & 15) * 8;
        int node = nb + row;
        float v[8];
        float ss = 0.f;
        if constexpr (!CONV2) {
            #pragma unroll
            for (int j = 0; j < 8; ++j) {
                v[j] = sC[row][cb + j] + bias1[cb + j];
                ss = fmaf(v[j], v[j], ss);
            }
        } else {
            float flag = (rowptr[node + 1] > rowptr[node]) ? 1.f : 0.f;
            #pragma unroll
            for (int j = 0; j < 8; ++j) {
                v[j] = sC[row][cb + j] + biasA[cb + j] + flag * biasE[128 + cb + j];
                ss = fmaf(v[j], v[j], ss);
            }
        }
        ss += __shfl_xor(ss, 1); ss += __shfl_xor(ss, 2);
        ss += __shfl_xor(ss, 4); ss += __shfl_xor(ss, 8);
        float sc = 1.f / fmaxf(sqrtf(ss), 1e-12f);

        if constexpr (!CONV2) {
            #pragma unroll
            for (int j = 0; j < 8; ++j) {
                v[j] = fmaxf(v[j] * sc, 0.f);       // normalize then relu
                sC[row][cb + j] = v[j];             // f32 for BN stats
            }
            uint4 p;
            p.x = pk2(v[0], v[1]); p.y = pk2(v[2], v[3]);
            p.z = pk2(v[4], v[5]); p.w = pk2(v[6], v[7]);
            *(uint4*)&h1[(size_t)node * F + cb] = p;
            __syncthreads();   // B3: normalized sC visible for stats
            #pragma unroll
            for (int r = 0; r < 8; ++r) {           // all 512 threads: 4 row-groups x 128 cols
                float h = sC[srow0 + r][scol];
                sAcc += h; s2Acc = fmaf(h, h, s2Acc);
            }
        } else {
            #pragma unroll
            for (int j = 0; j < 8; ++j) sC[row][cb + j] = v[j] * sc;
            __syncthreads();   // B3: normalized sC visible for fc
            {
                int n = t >> 4, c = t & 15;        // 512 threads = 32 nodes x 16 classes
                float s = bfc[c];
                for (int o = 0; o < F; o += 4) {
                    float4 h4 = *(const float4*)&sC[n][o];
                    float4 w4 = *(const float4*)&Wfc[c * F + o];
                    s += h4.x * w4.x + h4.y * w4.y + h4.z * w4.z + h4.w * w4.w;
                }
                out[(size_t)(nb + n) * NC + c] = s;
            }
        }
        // next iteration's B1 protects sC reuse and buffer swap
    }

    if constexpr (!CONV2) {
        atomicAdd(&stats[scol], sAcc);
        atomicAdd(&stats[F + scol], s2Acc);
    }
#undef STAGE_A
}

extern "C" void kernel_launch(void* const* d_in, const int* in_sizes, int n_in,
                              void* d_out, int out_size, void* d_ws, size_t ws_size,
                              hipStream_t stream) {
    const float* x     = (const float*)d_in[0];
    const int*   ei    = (const int*)d_in[1];
    const float* W1l   = (const float*)d_in[2];
    const float* b1l   = (const float*)d_in[3];
    const float* W1r   = (const float*)d_in[4];
    const float* gamma = (const float*)d_in[5];
    const float* beta  = (const float*)d_in[6];
    const float* W2l   = (const float*)d_in[7];
    const float* b2l   = (const float*)d_in[8];
    const float* W2r   = (const float*)d_in[9];
    const float* Wfc   = (const float*)d_in[10];
    const float* bfc   = (const float*)d_in[11];

    char* ws = (char*)d_ws;
    int*            rowptr = (int*)(ws + OFF_ROWPTR);
    int*            fill   = (int*)(ws + OFF_FILL);
    int*            bsum   = (int*)(ws + OFF_BSUM);
    int*            sorted = (int*)(ws + OFF_SORTED);
    float*          stats  = (float*)(ws + OFF_STATS);
    unsigned short* w1b    = (unsigned short*)(ws + OFF_W1B);
    unsigned short* w2b    = (unsigned short*)(ws + OFF_W2B);
    unsigned short* xb     = (unsigned short*)(ws + OFF_XB);   // xb then h1 (same rows)
    unsigned short* aggm   = (unsigned short*)(ws + OFF_AGGM);
    float*          biasAE = (float*)(ws + OFF_FILL);          // fill region dead after scatter
    float*          out    = (float*)d_out;

    k_prep<<<NN * F / (256 * 8), 256, 0, stream>>>(x, xb, W1l, W1r, w1b, fill, stats);
    k_hist<<<(NE + 255) / 256, 256, 0, stream>>>(ei, fill);
    k_scan1<<<40, 1024, 0, stream>>>(fill, rowptr, bsum);
    k_scan3<<<40, 1024, 0, stream>>>(rowptr, bsum, fill);
    k_scatter<<<(NE + 255) / 256, 256, 0, stream>>>(ei, fill, sorted);

    // conv1
    k_agg<<<NN / 4, 256, 0, stream>>>(xb, rowptr, sorted, aggm);
    k_gemm<0><<<NN / (NT * TPB), 512, 0, stream>>>(aggm, xb, w1b, b1l, nullptr, nullptr,
                                                   rowptr, xb, stats, nullptr, nullptr, nullptr);
    k_wprep2<<<256, 128, 0, stream>>>(W2l, W2r, b2l, gamma, beta, stats, w2b, biasAE);

    // conv2 (+ fused fc); h1 lives in xb buffer
    k_agg<<<NN / 4, 256, 0, stream>>>(xb, rowptr, sorted, aggm);
    k_gemm<1><<<NN / (NT * TPB), 512, 0, stream>>>(aggm, xb, w2b, nullptr, biasAE, biasAE,
                                                   rowptr, nullptr, nullptr, Wfc, bfc, out);
}

// Round 18
// 170.513 us; speedup vs baseline: 1.1116x; 1.1116x over previous
//
#include <hip/hip_runtime.h>

#define NN 40000
#define NE 640000
#define F 128
#define NC 16
#define NT 32    // nodes per tile
#define TPB 5    // tiles per persistent block (250 blocks x 5 x 32 = 40000)

typedef __attribute__((ext_vector_type(8))) short bf16x8;
typedef __attribute__((ext_vector_type(4))) float f32x4;

// ws layout (bytes); total 23501312 < proven 23632384
#define OFF_ROWPTR 0u
#define OFF_FILL   163968u     // NN ints; DEAD after k_scatter -> first 256 f32 reused as biasA/biasE
#define OFF_BSUM   327936u
#define OFF_SORTED 328192u
#define OFF_STATS  2888192u    // 512 f32: [sum][sumsq][..][..] (sums stay intact)
#define OFF_W1B    2890240u    // w1l | w1r bf16 [out][k] (64 KB)
#define OFF_W2B    2955776u    // w2l | w2r bf16 [out][k], BN-scaled (64 KB)
#define OFF_XB     3021312u    // NN*F bf16: xb, then h1 overwrites same rows
#define OFF_AGGM   13261312u   // NN*F bf16

// LDS regions (k_gemm)
#define SM_W   0u        // weights 64 KB (swizzled image)
#define SM_A0  65536u    // A dbuf 0: agg 8K | self 8K
#define SM_A1  81920u    // A dbuf 1
#define SM_C   98304u    // sC [32][132] f32 = 16896 B
#define SM_TOT 115200u

#define GLL(gsrc, ldst) \
    __builtin_amdgcn_global_load_lds((const __attribute__((address_space(1))) void*)(gsrc), \
        (__attribute__((address_space(3))) void*)(ldst), 16, 0, 0)

__device__ __forceinline__ unsigned short f2b(float f) {   // f32 -> bf16 RNE
    unsigned u = __builtin_bit_cast(unsigned, f);
    return (unsigned short)((u + 0x7fffu + ((u >> 16) & 1u)) >> 16);
}
__device__ __forceinline__ float b2f(unsigned short s) {
    return __builtin_bit_cast(float, (unsigned)s << 16);
}
__device__ __forceinline__ unsigned pk2(float lo, float hi) {
    return (unsigned)f2b(lo) | ((unsigned)f2b(hi) << 16);
}
__device__ __forceinline__ float blo(unsigned u) { return __builtin_bit_cast(float, u << 16); }
__device__ __forceinline__ float bhi(unsigned u) { return __builtin_bit_cast(float, u & 0xffff0000u); }

// Fused prep: x->bf16 (8 elems/thread), W1 -> bf16, zero fill+stats.
__global__ __launch_bounds__(256) void k_prep(const float* __restrict__ x, unsigned short* __restrict__ xb,
                                              const float* __restrict__ W1l, const float* __restrict__ W1r,
                                              unsigned short* __restrict__ w1b,
                                              int* __restrict__ fill, float* __restrict__ stats) {
    int gid = blockIdx.x * 256 + threadIdx.x;    // < 640000
    if (gid < NN) fill[gid] = 0;
    if (gid < 256) stats[gid] = 0.f;
    if (gid < 32768) {
        int m = gid >> 14, rc = gid & 16383;
        const float* src = m ? W1r : W1l;
        w1b[gid] = f2b(src[rc]);
    }
    int i = gid * 8;
    float4 lo = *(const float4*)&x[i];
    float4 hi = *(const float4*)&x[i + 4];
    uint4 o;
    o.x = pk2(lo.x, lo.y); o.y = pk2(lo.z, lo.w);
    o.z = pk2(hi.x, hi.y); o.w = pk2(hi.z, hi.w);
    *(uint4*)&xb[i] = o;
}

__global__ __launch_bounds__(256) void k_hist(const int* __restrict__ ei, int* __restrict__ cnt) {
    int e = blockIdx.x * 256 + threadIdx.x;
    if (e < NE) atomicAdd(&cnt[ei[NE + e]], 1);
}

__global__ __launch_bounds__(1024) void k_scan1(const int* __restrict__ cnt, int* __restrict__ rowptr,
                                                int* __restrict__ bsum) {
    __shared__ int wsum[16];
    int t = threadIdx.x, b = blockIdx.x;
    int idx = b * 1024 + t;
    int v = (idx < NN) ? cnt[idx] : 0;
    int lane = t & 63, w = t >> 6;
    int val = v;
    #pragma unroll
    for (int off = 1; off < 64; off <<= 1) { int u = __shfl_up(val, off); if (lane >= off) val += u; }
    if (lane == 63) wsum[w] = val;
    __syncthreads();
    if (w == 0) {
        int x = (lane < 16) ? wsum[lane] : 0;
        #pragma unroll
        for (int off = 1; off < 16; off <<= 1) { int u = __shfl_up(x, off); if (lane >= off) x += u; }
        if (lane < 16) wsum[lane] = x;
    }
    __syncthreads();
    int excl = val - v + (w > 0 ? wsum[w - 1] : 0);
    if (idx < NN) rowptr[idx] = excl;
    if (t == 1023) bsum[b] = wsum[15];
}

// scan2 folded in: every wave redundantly exclusive-scans the 40 block sums.
__global__ __launch_bounds__(1024) void k_scan3(int* __restrict__ rowptr, const int* __restrict__ bsum,
                                                int* __restrict__ fill) {
    int t = threadIdx.x, b = blockIdx.x;
    int lane = t & 63;
    int v = (lane < 40) ? bsum[lane] : 0;
    int val = v;
    #pragma unroll
    for (int off = 1; off < 64; off <<= 1) { int u = __shfl_up(val, off); if (lane >= off) val += u; }
    int base = __shfl(val - v, b);
    int idx = b * 1024 + t;
    if (idx < NN) {
        int r = rowptr[idx] + base;
        rowptr[idx] = r;
        fill[idx] = r;
    }
    if (b == 0 && t == 0) rowptr[NN] = NE;
}

__global__ __launch_bounds__(256) void k_scatter(const int* __restrict__ ei, int* __restrict__ fill,
                                                 int* __restrict__ sorted) {
    int e = blockIdx.x * 256 + threadIdx.x;
    if (e < NE) {
        int src = ei[e], dst = ei[NE + e];
        int pos = atomicAdd(&fill[dst], 1);
        sorted[pos] = src;
    }
}

// Parallel BN-fold: 256 blocks x 128 threads; block = (side, output col o).
__global__ __launch_bounds__(128) void k_wprep2(const float* __restrict__ W2l, const float* __restrict__ W2r,
                                                const float* __restrict__ b2l,
                                                const float* __restrict__ gamma, const float* __restrict__ beta,
                                                const float* __restrict__ stats,
                                                unsigned short* __restrict__ w2b,
                                                float* __restrict__ biasAE) {
    __shared__ float red[2];
    int b = blockIdx.x;
    int side = b >> 7, o = b & 127;   // side 0 = W2l (-> biasE), side 1 = W2r (-> biasA)
    int k = threadIdx.x;
    float mu  = stats[k] * (1.f / NN);
    float var = stats[F + k] * (1.f / NN) - mu * mu;
    float a = gamma[k] * rsqrtf(var + 1e-5f);
    float bb = beta[k] - mu * a;
    const float* W = side ? W2r : W2l;
    float w = W[o * F + k];
    w2b[(side ? 16384 : 0) + o * F + k] = f2b(w * a);
    float d = bb * w;
    #pragma unroll
    for (int off = 1; off < 64; off <<= 1) d += __shfl_xor(d, off);
    if ((k & 63) == 0) red[k >> 6] = d;
    __syncthreads();
    if (k == 0) {
        float dot = red[0] + red[1];
        if (side) biasAE[o] = b2l[o] + dot;        // bias2a (always applied)
        else      biasAE[128 + o] = dot;           // biasExtra (iff deg>0)
    }
}

// Gather (neighbor mean): one wave per node; quarter q, up to 4 rows in flight per lane.
__global__ __launch_bounds__(256) void k_agg(
    const unsigned short* __restrict__ featb,
    const int* __restrict__ rowptr, const int* __restrict__ sorted,
    unsigned short* __restrict__ aggm)
{
    int node = (blockIdx.x << 2) + (threadIdx.x >> 6);
    int lane = threadIdx.x & 63;
    int q = lane >> 4, li = lane & 15;
    int fo = li << 3;
    int e0 = rowptr[node], e1 = rowptr[node + 1];
    int deg = e1 - e0;
    float a0=0.f,a1=0.f,a2=0.f,a3=0.f,a4=0.f,a5=0.f,a6=0.f,a7=0.f;

#define ACC_EDGE(SRC) do { \
        uint4 u = *(const uint4*)&featb[(size_t)(SRC) * F + fo]; \
        a0 += blo(u.x); a1 += bhi(u.x); \
        a2 += blo(u.y); a3 += bhi(u.y); \
        a4 += blo(u.z); a5 += bhi(u.z); \
        a6 += blo(u.w); a7 += bhi(u.w); \
    } while (0)

    int e = e0;
    for (; e + 16 <= e1; e += 16) {
        int s0 = sorted[e + q];
        int s1 = sorted[e + 4 + q];
        int s2 = sorted[e + 8 + q];
        int s3 = sorted[e + 12 + q];
        ACC_EDGE(s0); ACC_EDGE(s1); ACC_EDGE(s2); ACC_EDGE(s3);
    }
    for (; e + 8 <= e1; e += 8) {
        int s0 = sorted[e + q];
        int s1 = sorted[e + 4 + q];
        ACC_EDGE(s0); ACC_EDGE(s1);
    }
    for (; e + 4 <= e1; e += 4) {
        int s0 = sorted[e + q];
        ACC_EDGE(s0);
    }
    if (e < e1 && q < (e1 - e)) {
        int s0 = sorted[e + q];
        ACC_EDGE(s0);
    }
#undef ACC_EDGE

    #pragma unroll
    for (int m = 16; m <= 32; m <<= 1) {
        a0 += __shfl_xor(a0, m); a1 += __shfl_xor(a1, m);
        a2 += __shfl_xor(a2, m); a3 += __shfl_xor(a3, m);
        a4 += __shfl_xor(a4, m); a5 += __shfl_xor(a5, m);
        a6 += __shfl_xor(a6, m); a7 += __shfl_xor(a7, m);
    }

    if (q == 0) {
        float inv = 1.f / (float)(deg > 1 ? deg : 1);
        uint4 o;
        o.x = pk2(a0 * inv, a1 * inv);
        o.y = pk2(a2 * inv, a3 * inv);
        o.z = pk2(a4 * inv, a5 * inv);
        o.w = pk2(a6 * inv, a7 * inv);
        *(uint4*)&aggm[(size_t)node * F + fo] = o;
    }
}

// Persistent MFMA dual GEMM — 512 threads / 8 waves per block (r15-proven).
// Wave w -> 16 cols [w*16, w*16+16), rows 0..31. Weights staged ONCE per block
// (async global_load_lds, linear dest + pre-swizzled src); 5 tiles with A dbuf.
template<int CONV2>
__global__ __launch_bounds__(512) void k_gemm(
    const unsigned short* __restrict__ aggm,
    const unsigned short* __restrict__ selfb,   // conv1: xb, conv2: h1
    const unsigned short* __restrict__ wb,      // wl | wr bf16 [out][k], 64KB
    const float* __restrict__ bias1,
    const float* __restrict__ biasA, const float* __restrict__ biasE,
    const int* __restrict__ rowptr,
    unsigned short* __restrict__ h1, float* __restrict__ stats,
    const float* __restrict__ Wfc, const float* __restrict__ bfc,
    float* __restrict__ out)
{
    __shared__ __align__(16) char smem[SM_TOT];
    int t = threadIdx.x;
    int nb0 = blockIdx.x * (NT * TPB);
    int w = t >> 6, lane = t & 63;
    int li = lane & 15, kg = lane >> 4;
    float (*sC)[132] = (float(*)[132])(smem + SM_C);

    // ---- weight stage (once): 8 async 1KB calls per wave ----
    {
        const char* wsrc = (const char*)wb;
        #pragma unroll
        for (int i = 0; i < 8; ++i) {
            unsigned Lb = (unsigned)(w * 8192 + i * 1024);
            unsigned s = Lb + (unsigned)lane * 16u;
            unsigned g = s ^ (((s >> 8) & 7u) << 4);
            GLL(wsrc + g, smem + Lb);
        }
    }

    // A tile stage: 16 KB over 8 waves (2 x 1KB each); waves 0-3 agg, waves 4-7 self
#define STAGE_A(TI, BUF) { \
        size_t rowb = (size_t)(nb0 + (TI) * NT) * 256u; \
        const char* src_ = (const char*)((w < 4) ? aggm : selfb) + rowb; \
        unsigned sub_ = (unsigned)((w & 3) * 2048); \
        _Pragma("unroll") \
        for (int i_ = 0; i_ < 2; ++i_) { \
            unsigned q_ = sub_ + (unsigned)(i_ * 1024); \
            unsigned s_ = q_ + (unsigned)lane * 16u; \
            unsigned g_ = s_ ^ (((s_ >> 8) & 7u) << 4); \
            GLL(src_ + g_, smem + (BUF) + ((w < 4) ? 0u : 8192u) + q_); \
        } }

    STAGE_A(0, SM_A0)
    __syncthreads();   // vmcnt drained before barrier: weights + tile0 in LDS

    float sAcc = 0.f, s2Acc = 0.f;   // conv1 BN stats, accumulated across tiles
    unsigned swz = ((unsigned)(li & 7) << 4);

    for (int tt = 0; tt < TPB; ++tt) {
        unsigned bufC = (tt & 1) ? SM_A1 : SM_A0;
        unsigned bufN = (tt & 1) ? SM_A0 : SM_A1;
        if (tt + 1 < TPB) STAGE_A(tt + 1, bufN)   // async, lands by next barrier

        int nb = nb0 + tt * NT;

        // ---- MFMA: wave w -> cols [w*16, w*16+16), rows 0..31 ----
        f32x4 acc0 = {0.f,0.f,0.f,0.f}, acc1 = {0.f,0.f,0.f,0.f};
        #pragma unroll
        for (int path = 0; path < 2; ++path) {
            unsigned aBase = bufC + (path ? 8192u : 0u);
            unsigned bBase = path ? 32768u : 0u;
            #pragma unroll
            for (int kc = 0; kc < 4; ++kc) {
                unsigned koff = (unsigned)(kg * 16 + kc * 64);
                bf16x8 a0 = *(const bf16x8*)(smem + aBase + (((unsigned)li * 256u + koff) ^ swz));
                bf16x8 a1 = *(const bf16x8*)(smem + aBase + (((unsigned)(16 + li) * 256u + koff) ^ swz));
                bf16x8 b0 = *(const bf16x8*)(smem + bBase + (((unsigned)(w * 16 + li) * 256u + koff) ^ swz));
                acc0 = __builtin_amdgcn_mfma_f32_16x16x32_bf16(a0, b0, acc0, 0, 0, 0);
                acc1 = __builtin_amdgcn_mfma_f32_16x16x32_bf16(a1, b0, acc1, 0, 0, 0);
            }
        }
        __syncthreads();   // B1: compute-cur done; next-tile async loads drained

        // ---- C -> sC (layout r6/r11-verified: reg r -> row kg*4+r, col li) ----
        #pragma unroll
        for (int r = 0; r < 4; ++r) {
            sC[kg * 4 + r][w * 16 + li]      = acc0[r];
            sC[16 + kg * 4 + r][w * 16 + li] = acc1[r];
        }
        __syncthreads();   // B2

        // ---- bias + row L2 norm: thread -> row t>>4, cols (t&15)*8..+8 ----
        int row = t >> 4, cb = (t & 15) * 8;
        int node = nb + row;
        float v[8];
        float ss = 0.f;
        if constexpr (!CONV2) {
            #pragma unroll
            for (int j = 0; j < 8; ++j) {
                v[j] = sC[row][cb + j] + bias1[cb + j];
                ss = fmaf(v[j], v[j], ss);
            }
        } else {
            float flag = (rowptr[node + 1] > rowptr[node]) ? 1.f : 0.f;
            #pragma unroll
            for (int j = 0; j < 8; ++j) {
                v[j] = sC[row][cb + j] + biasA[cb + j] + flag * biasE[128 + cb + j];
                ss = fmaf(v[j], v[j], ss);
            }
        }
        ss += __shfl_xor(ss, 1); ss += __shfl_xor(ss, 2);
        ss += __shfl_xor(ss, 4); ss += __shfl_xor(ss, 8);
        float sc = 1.f / fmaxf(sqrtf(ss), 1e-12f);

        if constexpr (!CONV2) {
            #pragma unroll
            for (int j = 0; j < 8; ++j) {
                v[j] = fmaxf(v[j] * sc, 0.f);       // normalize then relu
                sC[row][cb + j] = v[j];             // f32 for BN stats
            }
            uint4 p;
            p.x = pk2(v[0], v[1]); p.y = pk2(v[2], v[3]);
            p.z = pk2(v[4], v[5]); p.w = pk2(v[6], v[7]);
            *(uint4*)&h1[(size_t)node * F + cb] = p;
            __syncthreads();   // B3: normalized sC visible for stats
            if (t < F) {
                #pragma unroll
                for (int r = 0; r < NT; ++r) {
                    float h = sC[r][t];
                    sAcc += h; s2Acc = fmaf(h, h, s2Acc);
                }
            }
        } else {
            #pragma unroll
            for (int j = 0; j < 8; ++j) sC[row][cb + j] = v[j] * sc;
            __syncthreads();   // B3: normalized sC visible for fc
            {
                int n = t >> 4, c = t & 15;        // 512 threads = 32 nodes x 16 classes
                float s = bfc[c];
                for (int o = 0; o < F; o += 4) {
                    float4 h4 = *(const float4*)&sC[n][o];
                    float4 w4 = *(const float4*)&Wfc[c * F + o];
                    s += h4.x * w4.x + h4.y * w4.y + h4.z * w4.z + h4.w * w4.w;
                }
                out[(size_t)(nb + n) * NC + c] = s;
            }
        }
        // next iteration's B1 protects sC reuse and buffer swap
    }

    if constexpr (!CONV2) {
        if (t < F) {
            atomicAdd(&stats[t], sAcc);
            atomicAdd(&stats[F + t], s2Acc);
        }
    }
#undef STAGE_A
}

extern "C" void kernel_launch(void* const* d_in, const int* in_sizes, int n_in,
                              void* d_out, int out_size, void* d_ws, size_t ws_size,
                              hipStream_t stream) {
    const float* x     = (const float*)d_in[0];
    const int*   ei    = (const int*)d_in[1];
    const float* W1l   = (const float*)d_in[2];
    const float* b1l   = (const float*)d_in[3];
    const float* W1r   = (const float*)d_in[4];
    const float* gamma = (const float*)d_in[5];
    const float* beta  = (const float*)d_in[6];
    const float* W2l   = (const float*)d_in[7];
    const float* b2l   = (const float*)d_in[8];
    const float* W2r   = (const float*)d_in[9];
    const float* Wfc   = (const float*)d_in[10];
    const float* bfc   = (const float*)d_in[11];

    char* ws = (char*)d_ws;
    int*            rowptr = (int*)(ws + OFF_ROWPTR);
    int*            fill   = (int*)(ws + OFF_FILL);
    int*            bsum   = (int*)(ws + OFF_BSUM);
    int*            sorted = (int*)(ws + OFF_SORTED);
    float*          stats  = (float*)(ws + OFF_STATS);
    unsigned short* w1b    = (unsigned short*)(ws + OFF_W1B);
    unsigned short* w2b    = (unsigned short*)(ws + OFF_W2B);
    unsigned short* xb     = (unsigned short*)(ws + OFF_XB);   // xb then h1 (same rows)
    unsigned short* aggm   = (unsigned short*)(ws + OFF_AGGM);
    float*          biasAE = (float*)(ws + OFF_FILL);          // fill region dead after scatter
    float*          out    = (float*)d_out;

    k_prep<<<NN * F / (256 * 8), 256, 0, stream>>>(x, xb, W1l, W1r, w1b, fill, stats);
    k_hist<<<(NE + 255) / 256, 256, 0, stream>>>(ei, fill);
    k_scan1<<<40, 1024, 0, stream>>>(fill, rowptr, bsum);
    k_scan3<<<40, 1024, 0, stream>>>(rowptr, bsum, fill);
    k_scatter<<<(NE + 255) / 256, 256, 0, stream>>>(ei, fill, sorted);

    // conv1
    k_agg<<<NN / 4, 256, 0, stream>>>(xb, rowptr, sorted, aggm);
    k_gemm<0><<<NN / (NT * TPB), 512, 0, stream>>>(aggm, xb, w1b, b1l, nullptr, nullptr,
                                                   rowptr, xb, stats, nullptr, nullptr, nullptr);
    k_wprep2<<<256, 128, 0, stream>>>(W2l, W2r, b2l, gamma, beta, stats, w2b, biasAE);

    // conv2 (+ fused fc); h1 lives in xb buffer
    k_agg<<<NN / 4, 256, 0, stream>>>(xb, rowptr, sorted, aggm);
    k_gemm<1><<<NN / (NT * TPB), 512, 0, stream>>>(aggm, xb, w2b, nullptr, biasAE, biasAE,
                                                   rowptr, nullptr, nullptr, Wfc, bfc, out);
}

// Round 19
// 143.180 us; speedup vs baseline: 1.3238x; 1.1909x over previous
//
#include <hip/hip_runtime.h>

#define NN 40000
#define NE 640000
#define F 128
#define NC 16
#define NT 32    // nodes per tile
#define TPB 5    // tiles per persistent block (250 blocks x 5 x 32 = 40000)
#define NBKT 157 // CSR buckets: dst>>8, 256 nodes each (39999>>8 = 156)

typedef __attribute__((ext_vector_type(8))) short bf16x8;
typedef __attribute__((ext_vector_type(4))) float f32x4;

// ws layout (bytes); total 23501312 < proven 23632384
#define OFF_ROWPTR 0u
#define OFF_FILL   163968u     // 160KB scratch: biasAE[256 f32] @ +0; bhist @ +4096; bfill @ +8192; bbase @ +12288
#define OFF_SORTED 328192u
#define OFF_STATS  2888192u    // 512 f32: [sum][sumsq][..][..]
#define OFF_W1B    2890240u    // w1l | w1r bf16 [out][k] (64 KB)
#define OFF_W2B    2955776u    // w2l | w2r bf16 [out][k], BN-scaled (64 KB)
#define OFF_XB     3021312u    // NN*F bf16: xb, then h1 overwrites same rows
#define OFF_AGGM   13261312u   // NN*F bf16; first 2.56MB doubles as ebuf (dead before agg writes)

// LDS regions (k_gemm)
#define SM_W   0u        // weights 64 KB (swizzled image)
#define SM_A0  65536u    // A dbuf 0: agg 8K | self 8K
#define SM_A1  81920u    // A dbuf 1
#define SM_C   98304u    // sC [32][132] f32 = 16896 B
#define SM_TOT 115200u

#define GLL(gsrc, ldst) \
    __builtin_amdgcn_global_load_lds((const __attribute__((address_space(1))) void*)(gsrc), \
        (__attribute__((address_space(3))) void*)(ldst), 16, 0, 0)

__device__ __forceinline__ unsigned short f2b(float f) {   // f32 -> bf16 RNE
    unsigned u = __builtin_bit_cast(unsigned, f);
    return (unsigned short)((u + 0x7fffu + ((u >> 16) & 1u)) >> 16);
}
__device__ __forceinline__ float b2f(unsigned short s) {
    return __builtin_bit_cast(float, (unsigned)s << 16);
}
__device__ __forceinline__ unsigned pk2(float lo, float hi) {
    return (unsigned)f2b(lo) | ((unsigned)f2b(hi) << 16);
}
__device__ __forceinline__ float blo(unsigned u) { return __builtin_bit_cast(float, u << 16); }
__device__ __forceinline__ float bhi(unsigned u) { return __builtin_bit_cast(float, u & 0xffff0000u); }

// Fused prep: x->bf16, W1 -> bf16, zero stats + bucket hist.
__global__ __launch_bounds__(256) void k_prep(const float* __restrict__ x, unsigned short* __restrict__ xb,
                                              const float* __restrict__ W1l, const float* __restrict__ W1r,
                                              unsigned short* __restrict__ w1b,
                                              int* __restrict__ bhist, float* __restrict__ stats) {
    int gid = blockIdx.x * 256 + threadIdx.x;    // < 640000
    if (gid < NBKT) bhist[gid] = 0;
    if (gid < 256) stats[gid] = 0.f;
    if (gid < 32768) {
        int m = gid >> 14, rc = gid & 16383;
        const float* src = m ? W1r : W1l;
        w1b[gid] = f2b(src[rc]);
    }
    int i = gid * 8;
    float4 lo = *(const float4*)&x[i];
    float4 hi = *(const float4*)&x[i + 4];
    uint4 o;
    o.x = pk2(lo.x, lo.y); o.y = pk2(lo.z, lo.w);
    o.z = pk2(hi.x, hi.y); o.w = pk2(hi.z, hi.w);
    *(uint4*)&xb[i] = o;
}

// Bucket histogram: LDS-reduced (625 blocks x 1024 thr, 1 edge/thread exact).
__global__ __launch_bounds__(1024) void k_bhist(const int* __restrict__ ei, int* __restrict__ bhist) {
    __shared__ int h[NBKT];
    int t = threadIdx.x;
    if (t < NBKT) h[t] = 0;
    __syncthreads();
    int e = blockIdx.x * 1024 + t;
    atomicAdd(&h[ei[NE + e] >> 8], 1);
    __syncthreads();
    if (t < NBKT && h[t]) atomicAdd(&bhist[t], h[t]);
}

// Exclusive scan of 157 bucket counts -> bbase (bases) + bfill (running cursors).
__global__ __launch_bounds__(256) void k_bscan(const int* __restrict__ bhist,
                                               int* __restrict__ bbase, int* __restrict__ bfill) {
    __shared__ int buf[256];
    __shared__ int ws[4];
    int t = threadIdx.x;
    int lane = t & 63, w4 = t >> 6;
    int v = (t < NBKT) ? bhist[t] : 0;
    int val = v;
    #pragma unroll
    for (int o = 1; o < 64; o <<= 1) { int u = __shfl_up(val, o); if (lane >= o) val += u; }
    if (lane == 63) ws[w4] = val;
    __syncthreads();
    int wpre = 0;
    #pragma unroll
    for (int k = 0; k < 4; ++k) if (k < w4) wpre += ws[k];
    int excl = wpre + val - v;
    if (t < NBKT) { bbase[t] = excl; bfill[t] = excl; }
    if (t == 0) bbase[NBKT] = NE;
    (void)buf;
}

// Place edges into bucket regions as packed (dst16|src16). LDS rank + one global
// reservation atomic per (block,bucket) -> each block writes ~6.5-edge contiguous runs,
// ~300 active L2 lines/block -> write traffic ~6MB (old random scatter: 41MB granules).
__global__ __launch_bounds__(1024) void k_place(const int* __restrict__ ei, int* __restrict__ bfill,
                                                unsigned* __restrict__ ebuf) {
    __shared__ int h[NBKT];
    __shared__ int fl[NBKT];
    int t = threadIdx.x;
    if (t < NBKT) h[t] = 0;
    __syncthreads();
    int e = blockIdx.x * 1024 + t;
    int d = ei[NE + e], s = ei[e];
    int b = d >> 8;
    int r = atomicAdd(&h[b], 1);
    __syncthreads();
    if (t < NBKT && h[t]) fl[t] = atomicAdd(&bfill[t], h[t]);
    __syncthreads();
    ebuf[fl[b] + r] = ((unsigned)d << 16) | (unsigned)s;
}

// Within-bucket counting sort (157 blocks x 1024 thr): node hist + scan in LDS; writes
// sorted[] into the bucket's own 16KB L2-resident window + rowptr for its 256 nodes.
__global__ __launch_bounds__(1024) void k_passB(const unsigned* __restrict__ ebuf,
                                                const int* __restrict__ bbase,
                                                int* __restrict__ sorted, int* __restrict__ rowptr) {
    __shared__ int h[256];
    __shared__ int off[256];
    __shared__ int fl[256];
    __shared__ int ws[4];
    int b = blockIdx.x, t = threadIdx.x;
    int e0 = bbase[b], e1 = bbase[b + 1];
    if (t < 256) { h[t] = 0; fl[t] = 0; }
    __syncthreads();
    for (int e = e0 + t; e < e1; e += 1024)
        atomicAdd(&h[(ebuf[e] >> 16) & 255], 1);
    __syncthreads();
    int lane = t & 63, w4 = t >> 6;
    int v = (t < 256) ? h[t] : 0;
    int val = v;
    #pragma unroll
    for (int o = 1; o < 64; o <<= 1) { int u = __shfl_up(val, o); if (lane >= o) val += u; }
    if (t < 256 && lane == 63) ws[w4] = val;
    __syncthreads();
    if (t < 256) {
        int wpre = 0;
        #pragma unroll
        for (int k = 0; k < 4; ++k) if (k < w4) wpre += ws[k];
        off[t] = wpre + val - v;
    }
    __syncthreads();
    for (int e = e0 + t; e < e1; e += 1024) {
        unsigned pk = ebuf[e];
        int l = (pk >> 16) & 255;
        int r = atomicAdd(&fl[l], 1);
        sorted[e0 + off[l] + r] = (int)(pk & 0xFFFFu);
    }
    int node = b * 256 + t;
    if (t < 256 && node < NN) rowptr[node] = e0 + off[t];
    if (b == 0 && t == 0) rowptr[NN] = NE;
}

// Parallel BN-fold: 256 blocks x 128 threads; block = (side, output col o).
__global__ __launch_bounds__(128) void k_wprep2(const float* __restrict__ W2l, const float* __restrict__ W2r,
                                                const float* __restrict__ b2l,
                                                const float* __restrict__ gamma, const float* __restrict__ beta,
                                                const float* __restrict__ stats,
                                                unsigned short* __restrict__ w2b,
                                                float* __restrict__ biasAE) {
    __shared__ float red[2];
    int b = blockIdx.x;
    int side = b >> 7, o = b & 127;   // side 0 = W2l (-> biasE), side 1 = W2r (-> biasA)
    int k = threadIdx.x;
    float mu  = stats[k] * (1.f / NN);
    float var = stats[F + k] * (1.f / NN) - mu * mu;
    float a = gamma[k] * rsqrtf(var + 1e-5f);
    float bb = beta[k] - mu * a;
    const float* W = side ? W2r : W2l;
    float w = W[o * F + k];
    w2b[(side ? 16384 : 0) + o * F + k] = f2b(w * a);
    float d = bb * w;
    #pragma unroll
    for (int off = 1; off < 64; off <<= 1) d += __shfl_xor(d, off);
    if ((k & 63) == 0) red[k >> 6] = d;
    __syncthreads();
    if (k == 0) {
        float dot = red[0] + red[1];
        if (side) biasAE[o] = b2l[o] + dot;        // bias2a (always applied)
        else      biasAE[128 + o] = dot;           // biasExtra (iff deg>0)
    }
}

// Gather (neighbor mean): one wave per node; quarter q, up to 4 rows in flight per lane.
__global__ __launch_bounds__(256) void k_agg(
    const unsigned short* __restrict__ featb,
    const int* __restrict__ rowptr, const int* __restrict__ sorted,
    unsigned short* __restrict__ aggm)
{
    int node = (blockIdx.x << 2) + (threadIdx.x >> 6);
    int lane = threadIdx.x & 63;
    int q = lane >> 4, li = lane & 15;
    int fo = li << 3;
    int e0 = rowptr[node], e1 = rowptr[node + 1];
    int deg = e1 - e0;
    float a0=0.f,a1=0.f,a2=0.f,a3=0.f,a4=0.f,a5=0.f,a6=0.f,a7=0.f;

#define ACC_EDGE(SRC) do { \
        uint4 u = *(const uint4*)&featb[(size_t)(SRC) * F + fo]; \
        a0 += blo(u.x); a1 += bhi(u.x); \
        a2 += blo(u.y); a3 += bhi(u.y); \
        a4 += blo(u.z); a5 += bhi(u.z); \
        a6 += blo(u.w); a7 += bhi(u.w); \
    } while (0)

    int e = e0;
    for (; e + 16 <= e1; e += 16) {
        int s0 = sorted[e + q];
        int s1 = sorted[e + 4 + q];
        int s2 = sorted[e + 8 + q];
        int s3 = sorted[e + 12 + q];
        ACC_EDGE(s0); ACC_EDGE(s1); ACC_EDGE(s2); ACC_EDGE(s3);
    }
    for (; e + 8 <= e1; e += 8) {
        int s0 = sorted[e + q];
        int s1 = sorted[e + 4 + q];
        ACC_EDGE(s0); ACC_EDGE(s1);
    }
    for (; e + 4 <= e1; e += 4) {
        int s0 = sorted[e + q];
        ACC_EDGE(s0);
    }
    if (e < e1 && q < (e1 - e)) {
        int s0 = sorted[e + q];
        ACC_EDGE(s0);
    }
#undef ACC_EDGE

    #pragma unroll
    for (int m = 16; m <= 32; m <<= 1) {
        a0 += __shfl_xor(a0, m); a1 += __shfl_xor(a1, m);
        a2 += __shfl_xor(a2, m); a3 += __shfl_xor(a3, m);
        a4 += __shfl_xor(a4, m); a5 += __shfl_xor(a5, m);
        a6 += __shfl_xor(a6, m); a7 += __shfl_xor(a7, m);
    }

    if (q == 0) {
        float inv = 1.f / (float)(deg > 1 ? deg : 1);
        uint4 o;
        o.x = pk2(a0 * inv, a1 * inv);
        o.y = pk2(a2 * inv, a3 * inv);
        o.z = pk2(a4 * inv, a5 * inv);
        o.w = pk2(a6 * inv, a7 * inv);
        *(uint4*)&aggm[(size_t)node * F + fo] = o;
    }
}

// Persistent MFMA dual GEMM — 512 threads / 8 waves per block (r15-proven).
template<int CONV2>
__global__ __launch_bounds__(512) void k_gemm(
    const unsigned short* __restrict__ aggm,
    const unsigned short* __restrict__ selfb,   // conv1: xb, conv2: h1
    const unsigned short* __restrict__ wb,      // wl | wr bf16 [out][k], 64KB
    const float* __restrict__ bias1,
    const float* __restrict__ biasA, const float* __restrict__ biasE,
    const int* __restrict__ rowptr,
    unsigned short* __restrict__ h1, float* __restrict__ stats,
    const float* __restrict__ Wfc, const float* __restrict__ bfc,
    float* __restrict__ out)
{
    __shared__ __align__(16) char smem[SM_TOT];
    int t = threadIdx.x;
    int nb0 = blockIdx.x * (NT * TPB);
    int w = t >> 6, lane = t & 63;
    int li = lane & 15, kg = lane >> 4;
    float (*sC)[132] = (float(*)[132])(smem + SM_C);

    {
        const char* wsrc = (const char*)wb;
        #pragma unroll
        for (int i = 0; i < 8; ++i) {
            unsigned Lb = (unsigned)(w * 8192 + i * 1024);
            unsigned s = Lb + (unsigned)lane * 16u;
            unsigned g = s ^ (((s >> 8) & 7u) << 4);
            GLL(wsrc + g, smem + Lb);
        }
    }

#define STAGE_A(TI, BUF) { \
        size_t rowb = (size_t)(nb0 + (TI) * NT) * 256u; \
        const char* src_ = (const char*)((w < 4) ? aggm : selfb) + rowb; \
        unsigned sub_ = (unsigned)((w & 3) * 2048); \
        _Pragma("unroll") \
        for (int i_ = 0; i_ < 2; ++i_) { \
            unsigned q_ = sub_ + (unsigned)(i_ * 1024); \
            unsigned s_ = q_ + (unsigned)lane * 16u; \
            unsigned g_ = s_ ^ (((s_ >> 8) & 7u) << 4); \
            GLL(src_ + g_, smem + (BUF) + ((w < 4) ? 0u : 8192u) + q_); \
        } }

    STAGE_A(0, SM_A0)
    __syncthreads();

    float sAcc = 0.f, s2Acc = 0.f;
    unsigned swz = ((unsigned)(li & 7) << 4);

    for (int tt = 0; tt < TPB; ++tt) {
        unsigned bufC = (tt & 1) ? SM_A1 : SM_A0;
        unsigned bufN = (tt & 1) ? SM_A0 : SM_A1;
        if (tt + 1 < TPB) STAGE_A(tt + 1, bufN)

        int nb = nb0 + tt * NT;

        f32x4 acc0 = {0.f,0.f,0.f,0.f}, acc1 = {0.f,0.f,0.f,0.f};
        #pragma unroll
        for (int path = 0; path < 2; ++path) {
            unsigned aBase = bufC + (path ? 8192u : 0u);
            unsigned bBase = path ? 32768u : 0u;
            #pragma unroll
            for (int kc = 0; kc < 4; ++kc) {
                unsigned koff = (unsigned)(kg * 16 + kc * 64);
                bf16x8 a0 = *(const bf16x8*)(smem + aBase + (((unsigned)li * 256u + koff) ^ swz));
                bf16x8 a1 = *(const bf16x8*)(smem + aBase + (((unsigned)(16 + li) * 256u + koff) ^ swz));
                bf16x8 b0 = *(const bf16x8*)(smem + bBase + (((unsigned)(w * 16 + li) * 256u + koff) ^ swz));
                acc0 = __builtin_amdgcn_mfma_f32_16x16x32_bf16(a0, b0, acc0, 0, 0, 0);
                acc1 = __builtin_amdgcn_mfma_f32_16x16x32_bf16(a1, b0, acc1, 0, 0, 0);
            }
        }
        __syncthreads();

        #pragma unroll
        for (int r = 0; r < 4; ++r) {
            sC[kg * 4 + r][w * 16 + li]      = acc0[r];
            sC[16 + kg * 4 + r][w * 16 + li] = acc1[r];
        }
        __syncthreads();

        int row = t >> 4, cb = (t & 15) * 8;
        int node = nb + row;
        float v[8];
        float ss = 0.f;
        if constexpr (!CONV2) {
            #pragma unroll
            for (int j = 0; j < 8; ++j) {
                v[j] = sC[row][cb + j] + bias1[cb + j];
                ss = fmaf(v[j], v[j], ss);
            }
        } else {
            float flag = (rowptr[node + 1] > rowptr[node]) ? 1.f : 0.f;
            #pragma unroll
            for (int j = 0; j < 8; ++j) {
                v[j] = sC[row][cb + j] + biasA[cb + j] + flag * biasE[128 + cb + j];
                ss = fmaf(v[j], v[j], ss);
            }
        }
        ss += __shfl_xor(ss, 1); ss += __shfl_xor(ss, 2);
        ss += __shfl_xor(ss, 4); ss += __shfl_xor(ss, 8);
        float sc = 1.f / fmaxf(sqrtf(ss), 1e-12f);

        if constexpr (!CONV2) {
            #pragma unroll
            for (int j = 0; j < 8; ++j) {
                v[j] = fmaxf(v[j] * sc, 0.f);
                sC[row][cb + j] = v[j];
            }
            uint4 p;
            p.x = pk2(v[0], v[1]); p.y = pk2(v[2], v[3]);
            p.z = pk2(v[4], v[5]); p.w = pk2(v[6], v[7]);
            *(uint4*)&h1[(size_t)node * F + cb] = p;
            __syncthreads();
            if (t < F) {
                #pragma unroll
                for (int r = 0; r < NT; ++r) {
                    float h = sC[r][t];
                    sAcc += h; s2Acc = fmaf(h, h, s2Acc);
                }
            }
        } else {
            #pragma unroll
            for (int j = 0; j < 8; ++j) sC[row][cb + j] = v[j] * sc;
            __syncthreads();
            {
                int n = t >> 4, c = t & 15;
                float s = bfc[c];
                for (int o = 0; o < F; o += 4) {
                    float4 h4 = *(const float4*)&sC[n][o];
                    float4 w4 = *(const float4*)&Wfc[c * F + o];
                    s += h4.x * w4.x + h4.y * w4.y + h4.z * w4.z + h4.w * w4.w;
                }
                out[(size_t)(nb + n) * NC + c] = s;
            }
        }
    }

    if constexpr (!CONV2) {
        if (t < F) {
            atomicAdd(&stats[t], sAcc);
            atomicAdd(&stats[F + t], s2Acc);
        }
    }
#undef STAGE_A
}

extern "C" void kernel_launch(void* const* d_in, const int* in_sizes, int n_in,
                              void* d_out, int out_size, void* d_ws, size_t ws_size,
                              hipStream_t stream) {
    const float* x     = (const float*)d_in[0];
    const int*   ei    = (const int*)d_in[1];
    const float* W1l   = (const float*)d_in[2];
    const float* b1l   = (const float*)d_in[3];
    const float* W1r   = (const float*)d_in[4];
    const float* gamma = (const float*)d_in[5];
    const float* beta  = (const float*)d_in[6];
    const float* W2l   = (const float*)d_in[7];
    const float* b2l   = (const float*)d_in[8];
    const float* W2r   = (const float*)d_in[9];
    const float* Wfc   = (const float*)d_in[10];
    const float* bfc   = (const float*)d_in[11];

    char* ws = (char*)d_ws;
    int*            rowptr = (int*)(ws + OFF_ROWPTR);
    float*          biasAE = (float*)(ws + OFF_FILL);
    int*            bhist  = (int*)(ws + OFF_FILL + 4096);
    int*            bfill  = (int*)(ws + OFF_FILL + 8192);
    int*            bbase  = (int*)(ws + OFF_FILL + 12288);
    int*            sorted = (int*)(ws + OFF_SORTED);
    float*          stats  = (float*)(ws + OFF_STATS);
    unsigned short* w1b    = (unsigned short*)(ws + OFF_W1B);
    unsigned short* w2b    = (unsigned short*)(ws + OFF_W2B);
    unsigned short* xb     = (unsigned short*)(ws + OFF_XB);   // xb then h1 (same rows)
    unsigned short* aggm   = (unsigned short*)(ws + OFF_AGGM);
    unsigned*       ebuf   = (unsigned*)(ws + OFF_AGGM);       // dead before aggm is written
    float*          out    = (float*)d_out;

    k_prep<<<NN * F / (256 * 8), 256, 0, stream>>>(x, xb, W1l, W1r, w1b, bhist, stats);
    k_bhist<<<NE / 1024, 1024, 0, stream>>>(ei, bhist);
    k_bscan<<<1, 256, 0, stream>>>(bhist, bbase, bfill);
    k_place<<<NE / 1024, 1024, 0, stream>>>(ei, bfill, ebuf);
    k_passB<<<NBKT, 1024, 0, stream>>>(ebuf, bbase, sorted, rowptr);

    // conv1
    k_agg<<<NN / 4, 256, 0, stream>>>(xb, rowptr, sorted, aggm);
    k_gemm<0><<<NN / (NT * TPB), 512, 0, stream>>>(aggm, xb, w1b, b1l, nullptr, nullptr,
                                                   rowptr, xb, stats, nullptr, nullptr, nullptr);
    k_wprep2<<<256, 128, 0, stream>>>(W2l, W2r, b2l, gamma, beta, stats, w2b, biasAE);

    // conv2 (+ fused fc); h1 lives in xb buffer
    k_agg<<<NN / 4, 256, 0, stream>>>(xb, rowptr, sorted, aggm);
    k_gemm<1><<<NN / (NT * TPB), 512, 0, stream>>>(aggm, xb, w2b, nullptr, biasAE, biasAE,
                                                   rowptr, nullptr, nullptr, Wfc, bfc, out);
}

// Round 20
// 128.984 us; speedup vs baseline: 1.4695x; 1.1101x over previous
//
#include <hip/hip_runtime.h>

#define NN 40000
#define NE 640000
#define F 128
#define NC 16
#define NT 32    // nodes per tile
#define TPB 5    // tiles per persistent block (250 blocks x 5 x 32 = 40000)
#define NBKT 157 // CSR buckets: dst>>8, 256 nodes each
#define BCAP 8192 // fixed bucket capacity (mean 4076, +64 sigma — overflow impossible)

typedef __attribute__((ext_vector_type(8))) short bf16x8;
typedef __attribute__((ext_vector_type(4))) float f32x4;

// ws layout (bytes); total 23501312 < proven 23632384
#define OFF_ROWPTR 0u
#define OFF_FILL   163968u     // scratch: biasAE[256 f32] @ +0; bfill[157] @ +4096
#define OFF_SORTED 328192u
#define OFF_STATS  2888192u    // 512 f32: [sum][sumsq][..][..]
#define OFF_W1B    2890240u    // w1l | w1r bf16 [out][k] (64 KB)
#define OFF_W2B    2955776u    // w2l | w2r bf16 [out][k], BN-scaled (64 KB)
#define OFF_XB     3021312u    // NN*F bf16: xb, then h1 overwrites same rows
#define OFF_AGGM   13261312u   // NN*F bf16; first 5.1MB doubles as padded ebuf (dead before agg)

// LDS regions (k_gemm)
#define SM_W   0u
#define SM_A0  65536u
#define SM_A1  81920u
#define SM_C   98304u
#define SM_TOT 115200u

#define GLL(gsrc, ldst) \
    __builtin_amdgcn_global_load_lds((const __attribute__((address_space(1))) void*)(gsrc), \
        (__attribute__((address_space(3))) void*)(ldst), 16, 0, 0)

__device__ __forceinline__ unsigned short f2b(float f) {   // f32 -> bf16 RNE
    unsigned u = __builtin_bit_cast(unsigned, f);
    return (unsigned short)((u + 0x7fffu + ((u >> 16) & 1u)) >> 16);
}
__device__ __forceinline__ float b2f(unsigned short s) {
    return __builtin_bit_cast(float, (unsigned)s << 16);
}
__device__ __forceinline__ unsigned pk2(float lo, float hi) {
    return (unsigned)f2b(lo) | ((unsigned)f2b(hi) << 16);
}
__device__ __forceinline__ float blo(unsigned u) { return __builtin_bit_cast(float, u << 16); }
__device__ __forceinline__ float bhi(unsigned u) { return __builtin_bit_cast(float, u & 0xffff0000u); }

// Fused prep: x->bf16, W1 -> bf16, zero stats + bucket cursors.
__global__ __launch_bounds__(256) void k_prep(const float* __restrict__ x, unsigned short* __restrict__ xb,
                                              const float* __restrict__ W1l, const float* __restrict__ W1r,
                                              unsigned short* __restrict__ w1b,
                                              int* __restrict__ bfill, float* __restrict__ stats) {
    int gid = blockIdx.x * 256 + threadIdx.x;    // < 640000
    if (gid < NBKT) bfill[gid] = 0;
    if (gid < 256) stats[gid] = 0.f;
    if (gid < 32768) {
        int m = gid >> 14, rc = gid & 16383;
        const float* src = m ? W1r : W1l;
        w1b[gid] = f2b(src[rc]);
    }
    int i = gid * 8;
    float4 lo = *(const float4*)&x[i];
    float4 hi = *(const float4*)&x[i + 4];
    uint4 o;
    o.x = pk2(lo.x, lo.y); o.y = pk2(lo.z, lo.w);
    o.z = pk2(hi.x, hi.y); o.w = pk2(hi.z, hi.w);
    *(uint4*)&xb[i] = o;
}

// Single-pass bucket place: fixed bucket bases (t*BCAP), LDS rank + one reservation
// atomic per (block,bucket) on the prep-zeroed cursor. No histogram/scan kernels needed.
__global__ __launch_bounds__(1024) void k_place(const int* __restrict__ ei, int* __restrict__ bfill,
                                                unsigned* __restrict__ ebuf) {
    __shared__ int h[NBKT];
    __shared__ int fl[NBKT];
    int t = threadIdx.x;
    if (t < NBKT) h[t] = 0;
    __syncthreads();
    int e = blockIdx.x * 1024 + t;
    int d = ei[NE + e], s = ei[e];
    int b = d >> 8;
    int r = atomicAdd(&h[b], 1);
    __syncthreads();
    if (t < NBKT && h[t]) fl[t] = t * BCAP + atomicAdd(&bfill[t], h[t]);
    __syncthreads();
    ebuf[fl[b] + r] = ((unsigned)d << 16) | (unsigned)s;
}

// Within-bucket counting sort. bfill now holds complete bucket counts; each block
// scans them in-LDS to get its COMPACT global base, so sorted/rowptr stay contiguous.
__global__ __launch_bounds__(1024) void k_passB(const unsigned* __restrict__ ebuf,
                                                const int* __restrict__ bfill,
                                                int* __restrict__ sorted, int* __restrict__ rowptr) {
    __shared__ int h[256];
    __shared__ int off[256];
    __shared__ int fl[256];
    __shared__ int ws4[4];
    __shared__ int sE0;
    int b = blockIdx.x, t = threadIdx.x;
    int lane = t & 63, w4 = t >> 6;

    // compact base: exclusive prefix of bucket counts over buckets < b
    int v = 0, val = 0;
    if (t < 256) {
        v = (t < NBKT) ? bfill[t] : 0;
        val = v;
        #pragma unroll
        for (int o = 1; o < 64; o <<= 1) { int u = __shfl_up(val, o); if (lane >= o) val += u; }
        if (lane == 63) ws4[w4] = val;
        h[t] = 0; fl[t] = 0;
    }
    __syncthreads();
    if (t == b) {
        int wpre = 0;
        #pragma unroll
        for (int k = 0; k < 4; ++k) if (k < w4) wpre += ws4[k];
        sE0 = wpre + val - v;
    }
    __syncthreads();
    int e0 = sE0;
    int cnt = bfill[b];
    int src0 = b * BCAP;

    for (int i = t; i < cnt; i += 1024)
        atomicAdd(&h[(ebuf[src0 + i] >> 16) & 255], 1);
    __syncthreads();

    int v2 = (t < 256) ? h[t] : 0;
    int val2 = v2;
    if (t < 256) {
        #pragma unroll
        for (int o = 1; o < 64; o <<= 1) { int u = __shfl_up(val2, o); if (lane >= o) val2 += u; }
        if (lane == 63) ws4[w4] = val2;
    }
    __syncthreads();
    if (t < 256) {
        int wpre = 0;
        #pragma unroll
        for (int k = 0; k < 4; ++k) if (k < w4) wpre += ws4[k];
        off[t] = wpre + val2 - v2;
    }
    __syncthreads();

    for (int i = t; i < cnt; i += 1024) {
        unsigned pk = ebuf[src0 + i];
        int l = (pk >> 16) & 255;
        int r = atomicAdd(&fl[l], 1);
        sorted[e0 + off[l] + r] = (int)(pk & 0xFFFFu);
    }
    int node = b * 256 + t;
    if (t < 256 && node < NN) rowptr[node] = e0 + off[t];
    if (b == 0 && t == 0) rowptr[NN] = NE;
}

// Parallel BN-fold: 256 blocks x 128 threads; block = (side, output col o).
__global__ __launch_bounds__(128) void k_wprep2(const float* __restrict__ W2l, const float* __restrict__ W2r,
                                                const float* __restrict__ b2l,
                                                const float* __restrict__ gamma, const float* __restrict__ beta,
                                                const float* __restrict__ stats,
                                                unsigned short* __restrict__ w2b,
                                                float* __restrict__ biasAE) {
    __shared__ float red[2];
    int b = blockIdx.x;
    int side = b >> 7, o = b & 127;   // side 0 = W2l (-> biasE), side 1 = W2r (-> biasA)
    int k = threadIdx.x;
    float mu  = stats[k] * (1.f / NN);
    float var = stats[F + k] * (1.f / NN) - mu * mu;
    float a = gamma[k] * rsqrtf(var + 1e-5f);
    float bb = beta[k] - mu * a;
    const float* W = side ? W2r : W2l;
    float w = W[o * F + k];
    w2b[(side ? 16384 : 0) + o * F + k] = f2b(w * a);
    float d = bb * w;
    #pragma unroll
    for (int off = 1; off < 64; off <<= 1) d += __shfl_xor(d, off);
    if ((k & 63) == 0) red[k >> 6] = d;
    __syncthreads();
    if (k == 0) {
        float dot = red[0] + red[1];
        if (side) biasAE[o] = b2l[o] + dot;
        else      biasAE[128 + o] = dot;
    }
}

// Gather (neighbor mean): one wave per node; quarter q, up to 4 rows in flight per lane.
__global__ __launch_bounds__(256) void k_agg(
    const unsigned short* __restrict__ featb,
    const int* __restrict__ rowptr, const int* __restrict__ sorted,
    unsigned short* __restrict__ aggm)
{
    int node = (blockIdx.x << 2) + (threadIdx.x >> 6);
    int lane = threadIdx.x & 63;
    int q = lane >> 4, li = lane & 15;
    int fo = li << 3;
    int e0 = rowptr[node], e1 = rowptr[node + 1];
    int deg = e1 - e0;
    float a0=0.f,a1=0.f,a2=0.f,a3=0.f,a4=0.f,a5=0.f,a6=0.f,a7=0.f;

#define ACC_EDGE(SRC) do { \
        uint4 u = *(const uint4*)&featb[(size_t)(SRC) * F + fo]; \
        a0 += blo(u.x); a1 += bhi(u.x); \
        a2 += blo(u.y); a3 += bhi(u.y); \
        a4 += blo(u.z); a5 += bhi(u.z); \
        a6 += blo(u.w); a7 += bhi(u.w); \
    } while (0)

    int e = e0;
    for (; e + 16 <= e1; e += 16) {
        int s0 = sorted[e + q];
        int s1 = sorted[e + 4 + q];
        int s2 = sorted[e + 8 + q];
        int s3 = sorted[e + 12 + q];
        ACC_EDGE(s0); ACC_EDGE(s1); ACC_EDGE(s2); ACC_EDGE(s3);
    }
    for (; e + 8 <= e1; e += 8) {
        int s0 = sorted[e + q];
        int s1 = sorted[e + 4 + q];
        ACC_EDGE(s0); ACC_EDGE(s1);
    }
    for (; e + 4 <= e1; e += 4) {
        int s0 = sorted[e + q];
        ACC_EDGE(s0);
    }
    if (e < e1 && q < (e1 - e)) {
        int s0 = sorted[e + q];
        ACC_EDGE(s0);
    }
#undef ACC_EDGE

    #pragma unroll
    for (int m = 16; m <= 32; m <<= 1) {
        a0 += __shfl_xor(a0, m); a1 += __shfl_xor(a1, m);
        a2 += __shfl_xor(a2, m); a3 += __shfl_xor(a3, m);
        a4 += __shfl_xor(a4, m); a5 += __shfl_xor(a5, m);
        a6 += __shfl_xor(a6, m); a7 += __shfl_xor(a7, m);
    }

    if (q == 0) {
        float inv = 1.f / (float)(deg > 1 ? deg : 1);
        uint4 o;
        o.x = pk2(a0 * inv, a1 * inv);
        o.y = pk2(a2 * inv, a3 * inv);
        o.z = pk2(a4 * inv, a5 * inv);
        o.w = pk2(a6 * inv, a7 * inv);
        *(uint4*)&aggm[(size_t)node * F + fo] = o;
    }
}

// Persistent MFMA dual GEMM — 512 threads / 8 waves per block (r15-proven).
template<int CONV2>
__global__ __launch_bounds__(512) void k_gemm(
    const unsigned short* __restrict__ aggm,
    const unsigned short* __restrict__ selfb,   // conv1: xb, conv2: h1
    const unsigned short* __restrict__ wb,      // wl | wr bf16 [out][k], 64KB
    const float* __restrict__ bias1,
    const float* __restrict__ biasA, const float* __restrict__ biasE,
    const int* __restrict__ rowptr,
    unsigned short* __restrict__ h1, float* __restrict__ stats,
    const float* __restrict__ Wfc, const float* __restrict__ bfc,
    float* __restrict__ out)
{
    __shared__ __align__(16) char smem[SM_TOT];
    int t = threadIdx.x;
    int nb0 = blockIdx.x * (NT * TPB);
    int w = t >> 6, lane = t & 63;
    int li = lane & 15, kg = lane >> 4;
    float (*sC)[132] = (float(*)[132])(smem + SM_C);

    {
        const char* wsrc = (const char*)wb;
        #pragma unroll
        for (int i = 0; i < 8; ++i) {
            unsigned Lb = (unsigned)(w * 8192 + i * 1024);
            unsigned s = Lb + (unsigned)lane * 16u;
            unsigned g = s ^ (((s >> 8) & 7u) << 4);
            GLL(wsrc + g, smem + Lb);
        }
    }

#define STAGE_A(TI, BUF) { \
        size_t rowb = (size_t)(nb0 + (TI) * NT) * 256u; \
        const char* src_ = (const char*)((w < 4) ? aggm : selfb) + rowb; \
        unsigned sub_ = (unsigned)((w & 3) * 2048); \
        _Pragma("unroll") \
        for (int i_ = 0; i_ < 2; ++i_) { \
            unsigned q_ = sub_ + (unsigned)(i_ * 1024); \
            unsigned s_ = q_ + (unsigned)lane * 16u; \
            unsigned g_ = s_ ^ (((s_ >> 8) & 7u) << 4); \
            GLL(src_ + g_, smem + (BUF) + ((w < 4) ? 0u : 8192u) + q_); \
        } }

    STAGE_A(0, SM_A0)
    __syncthreads();

    float sAcc = 0.f, s2Acc = 0.f;
    unsigned swz = ((unsigned)(li & 7) << 4);

    for (int tt = 0; tt < TPB; ++tt) {
        unsigned bufC = (tt & 1) ? SM_A1 : SM_A0;
        unsigned bufN = (tt & 1) ? SM_A0 : SM_A1;
        if (tt + 1 < TPB) STAGE_A(tt + 1, bufN)

        int nb = nb0 + tt * NT;

        f32x4 acc0 = {0.f,0.f,0.f,0.f}, acc1 = {0.f,0.f,0.f,0.f};
        #pragma unroll
        for (int path = 0; path < 2; ++path) {
            unsigned aBase = bufC + (path ? 8192u : 0u);
            unsigned bBase = path ? 32768u : 0u;
            #pragma unroll
            for (int kc = 0; kc < 4; ++kc) {
                unsigned koff = (unsigned)(kg * 16 + kc * 64);
                bf16x8 a0 = *(const bf16x8*)(smem + aBase + (((unsigned)li * 256u + koff) ^ swz));
                bf16x8 a1 = *(const bf16x8*)(smem + aBase + (((unsigned)(16 + li) * 256u + koff) ^ swz));
                bf16x8 b0 = *(const bf16x8*)(smem + bBase + (((unsigned)(w * 16 + li) * 256u + koff) ^ swz));
                acc0 = __builtin_amdgcn_mfma_f32_16x16x32_bf16(a0, b0, acc0, 0, 0, 0);
                acc1 = __builtin_amdgcn_mfma_f32_16x16x32_bf16(a1, b0, acc1, 0, 0, 0);
            }
        }
        __syncthreads();

        #pragma unroll
        for (int r = 0; r < 4; ++r) {
            sC[kg * 4 + r][w * 16 + li]      = acc0[r];
            sC[16 + kg * 4 + r][w * 16 + li] = acc1[r];
        }
        __syncthreads();

        int row = t >> 4, cb = (t & 15) * 8;
        int node = nb + row;
        float v[8];
        float ss = 0.f;
        if constexpr (!CONV2) {
            #pragma unroll
            for (int j = 0; j < 8; ++j) {
                v[j] = sC[row][cb + j] + bias1[cb + j];
                ss = fmaf(v[j], v[j], ss);
            }
        } else {
            float flag = (rowptr[node + 1] > rowptr[node]) ? 1.f : 0.f;
            #pragma unroll
            for (int j = 0; j < 8; ++j) {
                v[j] = sC[row][cb + j] + biasA[cb + j] + flag * biasE[128 + cb + j];
                ss = fmaf(v[j], v[j], ss);
            }
        }
        ss += __shfl_xor(ss, 1); ss += __shfl_xor(ss, 2);
        ss += __shfl_xor(ss, 4); ss += __shfl_xor(ss, 8);
        float sc = 1.f / fmaxf(sqrtf(ss), 1e-12f);

        if constexpr (!CONV2) {
            #pragma unroll
            for (int j = 0; j < 8; ++j) {
                v[j] = fmaxf(v[j] * sc, 0.f);
                sC[row][cb + j] = v[j];
            }
            uint4 p;
            p.x = pk2(v[0], v[1]); p.y = pk2(v[2], v[3]);
            p.z = pk2(v[4], v[5]); p.w = pk2(v[6], v[7]);
            *(uint4*)&h1[(size_t)node * F + cb] = p;
            __syncthreads();
            if (t < F) {
                #pragma unroll
                for (int r = 0; r < NT; ++r) {
                    float h = sC[r][t];
                    sAcc += h; s2Acc = fmaf(h, h, s2Acc);
                }
            }
        } else {
            #pragma unroll
            for (int j = 0; j < 8; ++j) sC[row][cb + j] = v[j] * sc;
            __syncthreads();
            {
                int n = t >> 4, c = t & 15;
                float s = bfc[c];
                for (int o = 0; o < F; o += 4) {
                    float4 h4 = *(const float4*)&sC[n][o];
                    float4 w4 = *(const float4*)&Wfc[c * F + o];
                    s += h4.x * w4.x + h4.y * w4.y + h4.z * w4.z + h4.w * w4.w;
                }
                out[(size_t)(nb + n) * NC + c] = s;
            }
        }
    }

    if constexpr (!CONV2) {
        if (t < F) {
            atomicAdd(&stats[t], sAcc);
            atomicAdd(&stats[F + t], s2Acc);
        }
    }
#undef STAGE_A
}

extern "C" void kernel_launch(void* const* d_in, const int* in_sizes, int n_in,
                              void* d_out, int out_size, void* d_ws, size_t ws_size,
                              hipStream_t stream) {
    const float* x     = (const float*)d_in[0];
    const int*   ei    = (const int*)d_in[1];
    const float* W1l   = (const float*)d_in[2];
    const float* b1l   = (const float*)d_in[3];
    const float* W1r   = (const float*)d_in[4];
    const float* gamma = (const float*)d_in[5];
    const float* beta  = (const float*)d_in[6];
    const float* W2l   = (const float*)d_in[7];
    const float* b2l   = (const float*)d_in[8];
    const float* W2r   = (const float*)d_in[9];
    const float* Wfc   = (const float*)d_in[10];
    const float* bfc   = (const float*)d_in[11];

    char* ws = (char*)d_ws;
    int*            rowptr = (int*)(ws + OFF_ROWPTR);
    float*          biasAE = (float*)(ws + OFF_FILL);
    int*            bfill  = (int*)(ws + OFF_FILL + 4096);
    int*            sorted = (int*)(ws + OFF_SORTED);
    float*          stats  = (float*)(ws + OFF_STATS);
    unsigned short* w1b    = (unsigned short*)(ws + OFF_W1B);
    unsigned short* w2b    = (unsigned short*)(ws + OFF_W2B);
    unsigned short* xb     = (unsigned short*)(ws + OFF_XB);   // xb then h1 (same rows)
    unsigned short* aggm   = (unsigned short*)(ws + OFF_AGGM);
    unsigned*       ebuf   = (unsigned*)(ws + OFF_AGGM);       // padded buckets; dead before aggm
    float*          out    = (float*)d_out;

    k_prep<<<NN * F / (256 * 8), 256, 0, stream>>>(x, xb, W1l, W1r, w1b, bfill, stats);
    k_place<<<NE / 1024, 1024, 0, stream>>>(ei, bfill, ebuf);
    k_passB<<<NBKT, 1024, 0, stream>>>(ebuf, bfill, sorted, rowptr);

    // conv1
    k_agg<<<NN / 4, 256, 0, stream>>>(xb, rowptr, sorted, aggm);
    k_gemm<0><<<NN / (NT * TPB), 512, 0, stream>>>(aggm, xb, w1b, b1l, nullptr, nullptr,
                                                   rowptr, xb, stats, nullptr, nullptr, nullptr);
    k_wprep2<<<256, 128, 0, stream>>>(W2l, W2r, b2l, gamma, beta, stats, w2b, biasAE);

    // conv2 (+ fused fc); h1 lives in xb buffer
    k_agg<<<NN / 4, 256, 0, stream>>>(xb, rowptr, sorted, aggm);
    k_gemm<1><<<NN / (NT * TPB), 512, 0, stream>>>(aggm, xb, w2b, nullptr, biasAE, biasAE,
                                                   rowptr, nullptr, nullptr, Wfc, bfc, out);
}